// Round 1
// baseline (122.904 us; speedup 1.0000x reference)
//
#include <hip/hip_runtime.h>

// MedianPool2d: 3x3 median, stride 1, reflect padding, input [8,8,512,512] fp32.
// Memory-bound: 64 MiB in + 64 MiB out -> ~21 us roofline at 6.3 TB/s.

#define MP_H 512
#define MP_W 512

__device__ __forceinline__ void mnmx(float& a, float& b) {
    float t = fminf(a, b);
    b = fmaxf(a, b);
    a = t;
}

// Classic 19-exchange median-of-9 network (Paeth). Returns the median.
__device__ __forceinline__ float median9(float p0, float p1, float p2,
                                         float p3, float p4, float p5,
                                         float p6, float p7, float p8) {
    mnmx(p1, p2); mnmx(p4, p5); mnmx(p7, p8);
    mnmx(p0, p1); mnmx(p3, p4); mnmx(p6, p7);
    mnmx(p1, p2); mnmx(p4, p5); mnmx(p7, p8);
    mnmx(p0, p3); mnmx(p5, p8); mnmx(p4, p7);
    mnmx(p3, p6); mnmx(p1, p4); mnmx(p2, p5);
    mnmx(p4, p7); mnmx(p4, p2); mnmx(p6, p4);
    mnmx(p4, p2);
    return p4;
}

// Load 6 consecutive columns (x0-1 .. x0+4) of one row, reflect-clamped.
// x0 is a multiple of 4 in [0, 508]; the float4 at x0 is 16B-aligned.
__device__ __forceinline__ void load6(const float* __restrict__ rowp, int x0, float v[6]) {
    const float4 c = *reinterpret_cast<const float4*>(rowp + x0);
    v[1] = c.x; v[2] = c.y; v[3] = c.z; v[4] = c.w;
    const int xl = (x0 == 0)        ? 1        : x0 - 1;   // reflect: -1 -> 1
    const int xr = (x0 + 4 == MP_W) ? MP_W - 2 : x0 + 4;   // reflect: 512 -> 510
    v[0] = rowp[xl];
    v[5] = rowp[xr];
}

__global__ __launch_bounds__(256) void median3x3_kernel(const float* __restrict__ x,
                                                        float* __restrict__ out) {
    const int tid = blockIdx.x * 256 + threadIdx.x;
    const int x0  = (tid & 127) << 2;   // column group: 0..508 step 4
    const int row = tid >> 7;           // global row index over B*C*H
    const int y   = row & (MP_H - 1);
    const int bc  = row >> 9;           // which of the 64 images

    const float* base = x + ((size_t)bc << 18);   // 512*512 per image
    const int ym = (y == 0)        ? 1        : y - 1;   // reflect top
    const int yp = (y == MP_H - 1) ? MP_H - 2 : y + 1;   // reflect bottom

    float r0[6], r1[6], r2[6];
    load6(base + (size_t)ym * MP_W, x0, r0);
    load6(base + (size_t)y  * MP_W, x0, r1);
    load6(base + (size_t)yp * MP_W, x0, r2);

    float4 o;
    o.x = median9(r0[0], r0[1], r0[2], r1[0], r1[1], r1[2], r2[0], r2[1], r2[2]);
    o.y = median9(r0[1], r0[2], r0[3], r1[1], r1[2], r1[3], r2[1], r2[2], r2[3]);
    o.z = median9(r0[2], r0[3], r0[4], r1[2], r1[3], r1[4], r2[2], r2[3], r2[4]);
    o.w = median9(r0[3], r0[4], r0[5], r1[3], r1[4], r1[5], r2[3], r2[4], r2[5]);

    *reinterpret_cast<float4*>(out + (size_t)row * MP_W + x0) = o;
}

extern "C" void kernel_launch(void* const* d_in, const int* in_sizes, int n_in,
                              void* d_out, int out_size, void* d_ws, size_t ws_size,
                              hipStream_t stream) {
    const float* x = (const float*)d_in[0];
    float* out = (float*)d_out;
    // total output elements = 8*8*512*512 = 16777216; 4 per thread -> 4194304 threads
    const int n_threads = out_size / 4;
    const int block = 256;
    const int grid = n_threads / block;   // 16384
    median3x3_kernel<<<grid, block, 0, stream>>>(x, out);
}

// Round 2
// 114.718 us; speedup vs baseline: 1.0714x; 1.0714x over previous
//
#include <hip/hip_runtime.h>

// MedianPool2d 3x3, stride 1, reflect pad, [8,8,512,512] fp32.
// One wave spans a full 512-wide row (lane -> 8 cols), 4 output rows per thread.
// Horizontal halo via wave shuffles (no scalar edge loads); vertical column
// sort shared across the 3 horizontal windows per output.

#define MP_W 512
#define MP_H 512

__device__ __forceinline__ void mnmx(float& a, float& b) {
    const float t = fminf(a, b);
    b = fmaxf(a, b);
    a = t;
}

__device__ __forceinline__ float med3f(float a, float b, float c) {
    // median of 3: 4 ops
    return fmaxf(fminf(a, b), fminf(fmaxf(a, b), c));
}

__global__ __launch_bounds__(256) void median3x3_kernel(const float* __restrict__ x,
                                                        float* __restrict__ out) {
    const int tid  = blockIdx.x * 256 + threadIdx.x;
    const int lane = tid & 63;
    const int wv   = tid >> 6;      // wave id: 0..8191
    const int rg   = wv & 127;      // row group (4 rows each)
    const int bc   = wv >> 7;       // image index 0..63
    const int y0   = rg << 2;       // first output row
    const int x0   = lane << 3;     // first column (lane covers x0..x0+7)

    const float* base = x + ((size_t)bc << 18);   // 512*512 per image

    // v[r][0..9]: columns x0-1 .. x0+8 of input rows y0-1 .. y0+4 (reflected)
    float v[6][10];
    #pragma unroll
    for (int r = 0; r < 6; ++r) {
        int yy = y0 - 1 + r;
        yy = (yy < 0) ? 1 : (yy >= MP_H ? 2 * MP_H - 2 - yy : yy);  // reflect
        const float* rp = base + (size_t)yy * MP_W + x0;
        const float4 a = *reinterpret_cast<const float4*>(rp);
        const float4 b = *reinterpret_cast<const float4*>(rp + 4);
        v[r][1] = a.x; v[r][2] = a.y; v[r][3] = a.z; v[r][4] = a.w;
        v[r][5] = b.x; v[r][6] = b.y; v[r][7] = b.z; v[r][8] = b.w;
        // halo from neighbor lanes; wave spans the full row so only the
        // true image edges need reflect (lane 0 left, lane 63 right).
        float l  = __shfl_up(b.w, 1);    // x = x0-1
        float rr = __shfl_down(a.x, 1);  // x = x0+8
        if (lane == 0)  l  = a.y;        // reflect: x=-1 -> x=1
        if (lane == 63) rr = b.z;        // reflect: x=512 -> x=510
        v[r][0] = l; v[r][9] = rr;
    }

    float* o = out + ((size_t)bc << 18) + (size_t)y0 * MP_W + x0;

    #pragma unroll
    for (int r = 0; r < 4; ++r) {
        // sort each vertical triple (shared by 3 horizontal windows)
        float lo[10], mi[10], hi[10];
        #pragma unroll
        for (int j = 0; j < 10; ++j) {
            float a = v[r][j], b = v[r + 1][j], c = v[r + 2][j];
            mnmx(a, b); mnmx(a, c); mnmx(b, c);
            lo[j] = a; mi[j] = b; hi[j] = c;
        }
        float res[8];
        #pragma unroll
        for (int j = 0; j < 8; ++j) {
            const float L = fmaxf(fmaxf(lo[j], lo[j + 1]), lo[j + 2]);
            const float M = med3f(mi[j], mi[j + 1], mi[j + 2]);
            const float H = fminf(fminf(hi[j], hi[j + 1]), hi[j + 2]);
            res[j] = med3f(L, M, H);
        }
        *reinterpret_cast<float4*>(o + (size_t)r * MP_W) =
            make_float4(res[0], res[1], res[2], res[3]);
        *reinterpret_cast<float4*>(o + (size_t)r * MP_W + 4) =
            make_float4(res[4], res[5], res[6], res[7]);
    }
}

extern "C" void kernel_launch(void* const* d_in, const int* in_sizes, int n_in,
                              void* d_out, int out_size, void* d_ws, size_t ws_size,
                              hipStream_t stream) {
    const float* x = (const float*)d_in[0];
    float* out = (float*)d_out;
    // 32 outputs per thread -> 524288 threads -> 2048 blocks of 256
    const int n_threads = out_size / 32;
    const int block = 256;
    const int grid = n_threads / block;
    median3x3_kernel<<<grid, block, 0, stream>>>(x, out);
}

// Round 4
// 114.268 us; speedup vs baseline: 1.0756x; 1.0039x over previous
//
#include <hip/hip_runtime.h>

// MedianPool2d 3x3, stride 1, reflect pad, [8,8,512,512] fp32.
// Streaming rolling-window: one wave spans a full 512-wide row (lane -> 8 cols),
// 8 output rows per thread. 4-slot circular row buffer; row r+2 prefetched while
// computing row r so memory stays continuously busy. Halo via consume-time
// shuffles; nontemporal stores for the streaming output.

#define MP_W 512
#define MP_H 512

typedef float floatx4 __attribute__((ext_vector_type(4)));  // native vec for nontemporal

__device__ __forceinline__ void mnmx(float& a, float& b) {
    const float t = fminf(a, b);
    b = fmaxf(a, b);
    a = t;
}

__device__ __forceinline__ float med3f(float a, float b, float c) {
    return fmaxf(fminf(a, b), fminf(fmaxf(a, b), c));
}

__global__ __launch_bounds__(256) void median3x3_kernel(const float* __restrict__ x,
                                                        float* __restrict__ out) {
    const int tid  = blockIdx.x * 256 + threadIdx.x;
    const int lane = tid & 63;
    const int wv   = tid >> 6;     // 0..4095
    const int rg   = wv & 63;      // row group within image (8 rows each)
    const int bc   = wv >> 6;      // image 0..63
    const int y0   = rg << 3;
    const int x0   = lane << 3;

    const float* base  = x   + ((size_t)bc << 18);
    float*       obase = out + ((size_t)bc << 18) + (size_t)y0 * MP_W + x0;

    auto row_ptr = [&](int yy) -> const float* {
        yy = (yy < 0) ? -yy : (yy >= MP_H ? 2 * MP_H - 2 - yy : yy);  // reflect
        return base + (size_t)yy * MP_W + x0;
    };

    floatx4 bufA[4], bufB[4];  // circular row buffers (two float4 halves/row)
    {
        const float* rp;
        rp = row_ptr(y0 - 1); bufA[0] = *(const floatx4*)rp; bufB[0] = *(const floatx4*)(rp + 4);
        rp = row_ptr(y0);     bufA[1] = *(const floatx4*)rp; bufB[1] = *(const floatx4*)(rp + 4);
        rp = row_ptr(y0 + 1); bufA[2] = *(const floatx4*)rp; bufB[2] = *(const floatx4*)(rp + 4);
    }

    #pragma unroll
    for (int r = 0; r < 8; ++r) {
        // prefetch row y0+r+2 into the free slot (pure loads, no dependent ops)
        if (r < 7) {
            const float* rp = row_ptr(y0 + r + 2);
            bufA[(r + 3) & 3] = *(const floatx4*)rp;
            bufB[(r + 3) & 3] = *(const floatx4*)(rp + 4);
        }

        // assemble the 3 rows (with halo columns) for this output row
        float v[3][10];
        #pragma unroll
        for (int k = 0; k < 3; ++k) {
            const floatx4 a = bufA[(r + k) & 3];
            const floatx4 b = bufB[(r + k) & 3];
            v[k][1] = a.x; v[k][2] = a.y; v[k][3] = a.z; v[k][4] = a.w;
            v[k][5] = b.x; v[k][6] = b.y; v[k][7] = b.z; v[k][8] = b.w;
            float l = __shfl_up(b.w, 1);     // x0-1 from left neighbor lane
            float h = __shfl_down(a.x, 1);   // x0+8 from right neighbor lane
            if (lane == 0)  l = a.y;         // reflect: -1 -> 1
            if (lane == 63) h = b.z;         // reflect: 512 -> 510
            v[k][0] = l; v[k][9] = h;
        }

        // sort each vertical column triple (shared by 3 horizontal windows)
        float lo[10], mi[10], hi[10];
        #pragma unroll
        for (int j = 0; j < 10; ++j) {
            float a = v[0][j], b = v[1][j], c = v[2][j];
            mnmx(a, b); mnmx(a, c); mnmx(b, c);
            lo[j] = a; mi[j] = b; hi[j] = c;
        }

        float res[8];
        #pragma unroll
        for (int j = 0; j < 8; ++j) {
            const float L = fmaxf(fmaxf(lo[j], lo[j + 1]), lo[j + 2]);
            const float M = med3f(mi[j], mi[j + 1], mi[j + 2]);
            const float H = fminf(fminf(hi[j], hi[j + 1]), hi[j + 2]);
            res[j] = med3f(L, M, H);
        }

        float* op = obase + (size_t)r * MP_W;
        floatx4 o1 = {res[0], res[1], res[2], res[3]};
        floatx4 o2 = {res[4], res[5], res[6], res[7]};
        __builtin_nontemporal_store(o1, (floatx4*)op);
        __builtin_nontemporal_store(o2, (floatx4*)(op + 4));
    }
}

extern "C" void kernel_launch(void* const* d_in, const int* in_sizes, int n_in,
                              void* d_out, int out_size, void* d_ws, size_t ws_size,
                              hipStream_t stream) {
    const float* x = (const float*)d_in[0];
    float* out = (float*)d_out;
    // 64 outputs per thread -> 262144 threads -> 1024 blocks of 256
    const int n_threads = out_size / 64;
    const int block = 256;
    const int grid = n_threads / block;
    median3x3_kernel<<<grid, block, 0, stream>>>(x, out);
}